// Round 1
// baseline (3082.164 us; speedup 1.0000x reference)
//
#include <hip/hip_runtime.h>

constexpr int CH = 64;      // IN_CH == HID == 64
constexpr int NG = 64;      // graphs
constexpr int NC = 10;      // classes

// ---------------- scatter-add: agg[dst] += x[src] --------------------------
// 16 threads per edge, each does a float4 gather + 4 scalar atomics.
__global__ __launch_bounds__(256) void k_scatter(const float* __restrict__ x,
                                                 const int* __restrict__ src,
                                                 const int* __restrict__ dst,
                                                 float* __restrict__ agg,
                                                 int n_edges)
{
    long long t = (long long)blockIdx.x * 256 + threadIdx.x;
    long long total = (long long)n_edges * 16;
    if (t >= total) return;
    int e = (int)(t >> 4);
    int q = (int)(t & 15);
    int s = src[e];
    int d = dst[e];
    const float4 v = *(const float4*)(x + (size_t)s * CH + q * 4);
    float* a = agg + (size_t)d * CH + q * 4;
    atomicAdd(a + 0, v.x);
    atomicAdd(a + 1, v.y);
    atomicAdd(a + 2, v.z);
    atomicAdd(a + 3, v.w);
}

// -------- dense: out = relu(agg @ Wrel^T + x @ Wroot^T + b) ----------------
// one thread per (node, out_ch); W staged in LDS padded [64][65] (bank-free).
__global__ __launch_bounds__(256) void k_dense(const float* __restrict__ agg,
                                               const float* __restrict__ x,
                                               const float* __restrict__ Wrel,
                                               const float* __restrict__ Wroot,
                                               const float* __restrict__ bias,
                                               float* __restrict__ out,
                                               int n)
{
    __shared__ float sWrel[64 * 65];
    __shared__ float sWroot[64 * 65];
    __shared__ float sB[64];
    for (int idx = threadIdx.x; idx < 4096; idx += 256) {
        int o = idx >> 6, k = idx & 63;
        sWrel[o * 65 + k]  = Wrel[idx];
        sWroot[o * 65 + k] = Wroot[idx];
    }
    if (threadIdx.x < 64) sB[threadIdx.x] = bias[threadIdx.x];
    __syncthreads();

    int idx = blockIdx.x * 256 + threadIdx.x;
    int total = n * CH;
    if (idx >= total) return;
    int i = idx >> 6, o = idx & 63;
    const float4* ar = (const float4*)(agg + (size_t)i * CH);
    const float4* xr = (const float4*)(x + (size_t)i * CH);
    float acc = sB[o];
#pragma unroll
    for (int k4 = 0; k4 < 16; ++k4) {
        float4 a = ar[k4];
        float4 b = xr[k4];
        const float* wr = &sWrel[o * 65 + k4 * 4];
        const float* wt = &sWroot[o * 65 + k4 * 4];
        acc += a.x * wr[0] + a.y * wr[1] + a.z * wr[2] + a.w * wr[3];
        acc += b.x * wt[0] + b.y * wt[1] + b.z * wt[2] + b.w * wt[3];
    }
    out[idx] = fmaxf(acc, 0.f);
}

// -------- layer-2 dense fused with mean-pool accumulation ------------------
// block covers 64 rows; thread (rg,o) walks 16 contiguous rows, keeps a
// running per-graph accumulator (batch is sorted), flushes on graph change.
__global__ __launch_bounds__(256) void k_conv_pool(const float* __restrict__ agg,
                                                   const float* __restrict__ h,
                                                   const float* __restrict__ Wrel,
                                                   const float* __restrict__ Wroot,
                                                   const float* __restrict__ bias,
                                                   const int* __restrict__ batch,
                                                   float* __restrict__ sums,
                                                   int n)
{
    __shared__ float sWrel[64 * 65];
    __shared__ float sWroot[64 * 65];
    __shared__ float sB[64];
    for (int idx = threadIdx.x; idx < 4096; idx += 256) {
        int o = idx >> 6, k = idx & 63;
        sWrel[o * 65 + k]  = Wrel[idx];
        sWroot[o * 65 + k] = Wroot[idx];
    }
    if (threadIdx.x < 64) sB[threadIdx.x] = bias[threadIdx.x];
    __syncthreads();

    int o  = threadIdx.x & 63;
    int rg = threadIdx.x >> 6;               // 0..3
    int base = blockIdx.x * 64 + rg * 16;
    float acc = 0.f;
    int gcur = -1;
    for (int j = 0; j < 16; ++j) {
        int row = base + j;
        if (row >= n) break;
        int g = batch[row];
        const float4* ar = (const float4*)(agg + (size_t)row * CH);
        const float4* hr = (const float4*)(h + (size_t)row * CH);
        float v = sB[o];
#pragma unroll
        for (int k4 = 0; k4 < 16; ++k4) {
            float4 a = ar[k4];
            float4 b = hr[k4];
            const float* wr = &sWrel[o * 65 + k4 * 4];
            const float* wt = &sWroot[o * 65 + k4 * 4];
            v += a.x * wr[0] + a.y * wr[1] + a.z * wr[2] + a.w * wr[3];
            v += b.x * wt[0] + b.y * wt[1] + b.z * wt[2] + b.w * wt[3];
        }
        v = fmaxf(v, 0.f);
        if (g != gcur) {
            if (gcur >= 0) atomicAdd(&sums[gcur * CH + o], acc);
            acc = 0.f;
            gcur = g;
        }
        acc += v;
    }
    if (gcur >= 0) atomicAdd(&sums[gcur * CH + o], acc);
}

// -------- final: out[g,c] = (sums[g]/count[g]) . Wlin[c] + blin[c] ---------
__global__ void k_final(const float* __restrict__ sums,
                        const int* __restrict__ batch,
                        const float* __restrict__ Wlin,
                        const float* __restrict__ blin,
                        float* __restrict__ out,
                        int n_nodes)
{
    int t = threadIdx.x;
    if (t >= NG * NC) return;
    int g = t / NC, c = t % NC;
    // count nodes of graph g via binary search on sorted batch
    int lo = 0, hi = n_nodes;
    while (lo < hi) { int mid = (lo + hi) >> 1; if (batch[mid] < g) lo = mid + 1; else hi = mid; }
    int lb = lo;
    lo = 0; hi = n_nodes;
    while (lo < hi) { int mid = (lo + hi) >> 1; if (batch[mid] < g + 1) lo = mid + 1; else hi = mid; }
    int cnt = lo - lb;
    float inv = 1.0f / fmaxf((float)cnt, 1.0f);
    float acc = blin[c];
    for (int k = 0; k < CH; ++k)
        acc += sums[g * CH + k] * inv * Wlin[c * CH + k];
    out[g * NC + c] = acc;
}

extern "C" void kernel_launch(void* const* d_in, const int* in_sizes, int n_in,
                              void* d_out, int out_size, void* d_ws, size_t ws_size,
                              hipStream_t stream)
{
    const float* x      = (const float*)d_in[0];
    const int*   ei     = (const int*)d_in[1];
    const int*   batch  = (const int*)d_in[2];
    const float* W1rel  = (const float*)d_in[3];
    const float* W1root = (const float*)d_in[4];
    const float* b1     = (const float*)d_in[5];
    const float* W2rel  = (const float*)d_in[6];
    const float* W2root = (const float*)d_in[7];
    const float* b2     = (const float*)d_in[8];
    const float* Wlin   = (const float*)d_in[9];
    const float* blin   = (const float*)d_in[10];
    float* out = (float*)d_out;

    int n_nodes = in_sizes[0] / CH;
    int n_edges = in_sizes[1] / 2;
    const int* src = ei;
    const int* dst = ei + n_edges;

    float* bufA = (float*)d_ws;                         // agg1 / agg2
    float* bufB = bufA + (size_t)n_nodes * CH;          // h1
    float* sums = bufB + (size_t)n_nodes * CH;          // [NG][CH]

    size_t big = (size_t)n_nodes * CH * sizeof(float);
    hipMemsetAsync(bufA, 0, big, stream);
    hipMemsetAsync(sums, 0, NG * CH * sizeof(float), stream);

    long long sc_total = (long long)n_edges * 16;
    int sc_blocks = (int)((sc_total + 255) / 256);
    int dn_blocks = (n_nodes * CH + 255) / 256;
    int pl_blocks = (n_nodes + 63) / 64;

    // layer 1
    k_scatter<<<sc_blocks, 256, 0, stream>>>(x, src, dst, bufA, n_edges);
    k_dense<<<dn_blocks, 256, 0, stream>>>(bufA, x, W1rel, W1root, b1, bufB, n_nodes);
    // layer 2
    hipMemsetAsync(bufA, 0, big, stream);
    k_scatter<<<sc_blocks, 256, 0, stream>>>(bufB, src, dst, bufA, n_edges);
    k_conv_pool<<<pl_blocks, 256, 0, stream>>>(bufA, bufB, W2rel, W2root, b2, batch, sums, n_nodes);
    // head
    k_final<<<1, NG * NC, 0, stream>>>(sums, batch, Wlin, blin, out, n_nodes);
}

// Round 2
// 770.618 us; speedup vs baseline: 3.9996x; 3.9996x over previous
//
#include <hip/hip_runtime.h>

constexpr int CH = 64;      // IN_CH == HID == 64
constexpr int NG = 64;      // graphs
constexpr int NC = 10;      // classes

__device__ __forceinline__ float rlane(float v, int l) {
    return __int_as_float(__builtin_amdgcn_readlane(__float_as_int(v), l));
}

// ---------------- CSR build: degree histogram --------------------------------
__global__ __launch_bounds__(256) void k_deg(const int* __restrict__ dst,
                                             int* __restrict__ deg, int n_edges)
{
    int e = blockIdx.x * 256 + threadIdx.x;
    if (e < n_edges) atomicAdd(&deg[dst[e]], 1);
}

// ---------------- CSR build: exclusive scan (single block, 1024 thr) ---------
__global__ __launch_bounds__(1024) void k_scan(const int* __restrict__ deg,
                                               int* __restrict__ rowptr, int n)
{
    __shared__ int part[1024];
    int t = threadIdx.x;
    int chunk = (n + 1023) >> 10;
    int b = t * chunk;
    int e = min(b + chunk, n);
    int s = 0;
    for (int i = b; i < e; ++i) s += deg[i];
    part[t] = s;
    __syncthreads();
    // Hillis-Steele inclusive scan
    for (int off = 1; off < 1024; off <<= 1) {
        int v = (t >= off) ? part[t - off] : 0;
        __syncthreads();
        part[t] += v;
        __syncthreads();
    }
    int run = (t == 0) ? 0 : part[t - 1];
    for (int i = b; i < e; ++i) { rowptr[i] = run; run += deg[i]; }
    if (b <= n && e == n) rowptr[n] = run;   // total
}

// ---------------- CSR build: fill edge lists ---------------------------------
__global__ __launch_bounds__(256) void k_fill(const int* __restrict__ src,
                                              const int* __restrict__ dst,
                                              const int* __restrict__ rowptr,
                                              int* __restrict__ cursor,
                                              int* __restrict__ csr, int n_edges)
{
    int e = blockIdx.x * 256 + threadIdx.x;
    if (e >= n_edges) return;
    int d = dst[e];
    int pos = atomicAdd(&cursor[d], 1);
    csr[rowptr[d] + pos] = src[e];
}

// -------- fused gather + dense: out = relu(agg@Wrel^T + x@Wroot^T + b) -------
// one wave per node (grid-stride), lane = channel. W rows held in VGPRs;
// cross-lane k-broadcast via v_readlane (static indices, fully unrolled).
__global__ __launch_bounds__(256) void k_conv1(const float* __restrict__ x,
                                               const int* __restrict__ rowptr,
                                               const int* __restrict__ csr,
                                               const float* __restrict__ Wrel,
                                               const float* __restrict__ Wroot,
                                               const float* __restrict__ bias,
                                               float* __restrict__ out, int n)
{
    int lane = threadIdx.x & 63;
    float4 wrel[16], wroot[16];
    const float4* Wr = (const float4*)(Wrel + lane * CH);
    const float4* Wt = (const float4*)(Wroot + lane * CH);
#pragma unroll
    for (int i = 0; i < 16; ++i) { wrel[i] = Wr[i]; wroot[i] = Wt[i]; }
    float bv = bias[lane];

    int wavesTotal = gridDim.x * 4;
    for (int node = blockIdx.x * 4 + (threadIdx.x >> 6); node < n; node += wavesTotal) {
        int e0 = rowptr[node], e1 = rowptr[node + 1];
        float acc0 = 0.f, acc1 = 0.f, acc2 = 0.f, acc3 = 0.f;
        int e = e0;
        for (; e + 4 <= e1; e += 4) {
            int s0 = csr[e + 0], s1 = csr[e + 1], s2 = csr[e + 2], s3 = csr[e + 3];
            acc0 += x[(size_t)s0 * CH + lane];
            acc1 += x[(size_t)s1 * CH + lane];
            acc2 += x[(size_t)s2 * CH + lane];
            acc3 += x[(size_t)s3 * CH + lane];
        }
        for (; e < e1; ++e) acc0 += x[(size_t)csr[e] * CH + lane];
        float acc = (acc0 + acc1) + (acc2 + acc3);
        float xv = x[(size_t)node * CH + lane];

        float h = bv;
#pragma unroll
        for (int i = 0; i < 16; ++i) {
            float4 wr = wrel[i], wt = wroot[i];
            h += rlane(acc, 4 * i + 0) * wr.x + rlane(xv, 4 * i + 0) * wt.x;
            h += rlane(acc, 4 * i + 1) * wr.y + rlane(xv, 4 * i + 1) * wt.y;
            h += rlane(acc, 4 * i + 2) * wr.z + rlane(xv, 4 * i + 2) * wt.z;
            h += rlane(acc, 4 * i + 3) * wr.w + rlane(xv, 4 * i + 3) * wt.w;
        }
        out[(size_t)node * CH + lane] = fmaxf(h, 0.f);
    }
}

// -------- layer-2 fused gather + dense + mean-pool accumulation --------------
// contiguous node chunk per wave; running per-graph accumulator (batch sorted).
__global__ __launch_bounds__(256) void k_conv2(const float* __restrict__ h1,
                                               const int* __restrict__ rowptr,
                                               const int* __restrict__ csr,
                                               const float* __restrict__ Wrel,
                                               const float* __restrict__ Wroot,
                                               const float* __restrict__ bias,
                                               const int* __restrict__ batch,
                                               float* __restrict__ sums,
                                               int n, int chunk)
{
    int lane = threadIdx.x & 63;
    float4 wrel[16], wroot[16];
    const float4* Wr = (const float4*)(Wrel + lane * CH);
    const float4* Wt = (const float4*)(Wroot + lane * CH);
#pragma unroll
    for (int i = 0; i < 16; ++i) { wrel[i] = Wr[i]; wroot[i] = Wt[i]; }
    float bv = bias[lane];

    int w = blockIdx.x * 4 + (threadIdx.x >> 6);
    int nb = w * chunk;
    int ne = min(nb + chunk, n);
    float accRun = 0.f;
    int gcur = -1;
    for (int node = nb; node < ne; ++node) {
        int e0 = rowptr[node], e1 = rowptr[node + 1];
        float acc0 = 0.f, acc1 = 0.f, acc2 = 0.f, acc3 = 0.f;
        int e = e0;
        for (; e + 4 <= e1; e += 4) {
            int s0 = csr[e + 0], s1 = csr[e + 1], s2 = csr[e + 2], s3 = csr[e + 3];
            acc0 += h1[(size_t)s0 * CH + lane];
            acc1 += h1[(size_t)s1 * CH + lane];
            acc2 += h1[(size_t)s2 * CH + lane];
            acc3 += h1[(size_t)s3 * CH + lane];
        }
        for (; e < e1; ++e) acc0 += h1[(size_t)csr[e] * CH + lane];
        float acc = (acc0 + acc1) + (acc2 + acc3);
        float xv = h1[(size_t)node * CH + lane];

        float h = bv;
#pragma unroll
        for (int i = 0; i < 16; ++i) {
            float4 wr = wrel[i], wt = wroot[i];
            h += rlane(acc, 4 * i + 0) * wr.x + rlane(xv, 4 * i + 0) * wt.x;
            h += rlane(acc, 4 * i + 1) * wr.y + rlane(xv, 4 * i + 1) * wt.y;
            h += rlane(acc, 4 * i + 2) * wr.z + rlane(xv, 4 * i + 2) * wt.z;
            h += rlane(acc, 4 * i + 3) * wr.w + rlane(xv, 4 * i + 3) * wt.w;
        }
        h = fmaxf(h, 0.f);

        int g = batch[node];
        if (g != gcur) {
            if (gcur >= 0) atomicAdd(&sums[gcur * CH + lane], accRun);
            accRun = 0.f;
            gcur = g;
        }
        accRun += h;
    }
    if (gcur >= 0) atomicAdd(&sums[gcur * CH + lane], accRun);
}

// -------- final: out[g,c] = (sums[g]/count[g]) . Wlin[c] + blin[c] -----------
__global__ void k_final(const float* __restrict__ sums,
                        const int* __restrict__ batch,
                        const float* __restrict__ Wlin,
                        const float* __restrict__ blin,
                        float* __restrict__ out, int n_nodes)
{
    int t = threadIdx.x;
    if (t >= NG * NC) return;
    int g = t / NC, c = t % NC;
    int lo = 0, hi = n_nodes;
    while (lo < hi) { int mid = (lo + hi) >> 1; if (batch[mid] < g) lo = mid + 1; else hi = mid; }
    int lb = lo;
    lo = 0; hi = n_nodes;
    while (lo < hi) { int mid = (lo + hi) >> 1; if (batch[mid] < g + 1) lo = mid + 1; else hi = mid; }
    int cnt = lo - lb;
    float inv = 1.0f / fmaxf((float)cnt, 1.0f);
    float acc = blin[c];
    for (int k = 0; k < CH; ++k)
        acc += sums[g * CH + k] * inv * Wlin[c * CH + k];
    out[g * NC + c] = acc;
}

extern "C" void kernel_launch(void* const* d_in, const int* in_sizes, int n_in,
                              void* d_out, int out_size, void* d_ws, size_t ws_size,
                              hipStream_t stream)
{
    const float* x      = (const float*)d_in[0];
    const int*   ei     = (const int*)d_in[1];
    const int*   batch  = (const int*)d_in[2];
    const float* W1rel  = (const float*)d_in[3];
    const float* W1root = (const float*)d_in[4];
    const float* b1     = (const float*)d_in[5];
    const float* W2rel  = (const float*)d_in[6];
    const float* W2root = (const float*)d_in[7];
    const float* b2     = (const float*)d_in[8];
    const float* Wlin   = (const float*)d_in[9];
    const float* blin   = (const float*)d_in[10];
    float* out = (float*)d_out;

    int n_nodes = in_sizes[0] / CH;
    int n_edges = in_sizes[1] / 2;
    const int* src = ei;
    const int* dst = ei + n_edges;

    // workspace layout (~33 MB)
    float* h1     = (float*)d_ws;                          // n*64 f32
    int*   rowptr = (int*)(h1 + (size_t)n_nodes * CH);     // n+1
    int*   cursor = rowptr + (n_nodes + 1);                // n
    int*   csr    = cursor + n_nodes;                      // n_edges
    float* sums   = (float*)(csr + n_edges);               // NG*CH

    int eb = (n_edges + 255) / 256;

    // ---- build CSR (dst -> srcs) ----
    hipMemsetAsync(cursor, 0, n_nodes * sizeof(int), stream);
    k_deg<<<eb, 256, 0, stream>>>(dst, cursor, n_edges);
    k_scan<<<1, 1024, 0, stream>>>(cursor, rowptr, n_nodes);
    hipMemsetAsync(cursor, 0, n_nodes * sizeof(int), stream);
    k_fill<<<eb, 256, 0, stream>>>(src, dst, rowptr, cursor, csr, n_edges);

    // ---- layer 1 (fused gather + dense + relu) ----
    k_conv1<<<2048, 256, 0, stream>>>(x, rowptr, csr, W1rel, W1root, b1, h1, n_nodes);

    // ---- layer 2 (fused gather + dense + relu + pool-accumulate) ----
    hipMemsetAsync(sums, 0, NG * CH * sizeof(float), stream);
    int wavesTotal = 2048 * 4;
    int chunk = (n_nodes + wavesTotal - 1) / wavesTotal;
    k_conv2<<<2048, 256, 0, stream>>>(h1, rowptr, csr, W2rel, W2root, b2, batch, sums, n_nodes, chunk);

    // ---- head ----
    k_final<<<1, NG * NC, 0, stream>>>(sums, batch, Wlin, blin, out, n_nodes);
}

// Round 3
// 674.653 us; speedup vs baseline: 4.5685x; 1.1422x over previous
//
#include <hip/hip_runtime.h>

constexpr int CH = 64;      // IN_CH == HID == 64
constexpr int NG = 64;      // graphs
constexpr int NC = 10;      // classes

__device__ __forceinline__ float rlane(float v, int l) {
    return __int_as_float(__builtin_amdgcn_readlane(__float_as_int(v), l));
}
__device__ __forceinline__ void f4add(float4& a, const float4 v) {
    a.x += v.x; a.y += v.y; a.z += v.z; a.w += v.w;
}

// ---------------- CSR build ------------------------------------------------
__global__ __launch_bounds__(256) void k_deg(const int* __restrict__ dst,
                                             int* __restrict__ deg, int n_edges)
{
    int e = blockIdx.x * 256 + threadIdx.x;
    if (e < n_edges) atomicAdd(&deg[dst[e]], 1);
}

// exclusive scan; writes rowptr[n+1] and converts deg buffer into cursor
__global__ __launch_bounds__(1024) void k_scan(int* deg_cursor,
                                               int* __restrict__ rowptr, int n)
{
    __shared__ int part[1024];
    int t = threadIdx.x;
    int chunk = (n + 1023) >> 10;
    int b = t * chunk, e = min(b + chunk, n);
    int s = 0;
    for (int i = b; i < e; ++i) s += deg_cursor[i];
    part[t] = s;
    __syncthreads();
    for (int off = 1; off < 1024; off <<= 1) {
        int v = (t >= off) ? part[t - off] : 0;
        __syncthreads();
        part[t] += v;
        __syncthreads();
    }
    int run = (t == 0) ? 0 : part[t - 1];
    for (int i = b; i < e; ++i) {
        int d = deg_cursor[i];          // read BEFORE overwrite (same buffer)
        rowptr[i] = run;
        deg_cursor[i] = run;            // cursor = absolute start offset
        run += d;
    }
    if (e == n) rowptr[n] = run;
}

__global__ __launch_bounds__(256) void k_fill(const int* __restrict__ src,
                                              const int* __restrict__ dst,
                                              int* __restrict__ cursor,
                                              int* __restrict__ csr, int n_edges)
{
    int e = blockIdx.x * 256 + threadIdx.x;
    if (e >= n_edges) return;
    int pos = atomicAdd(&cursor[dst[e]], 1);
    csr[pos] = src[e];
}

// -------- streaming dense: Y = in@Wrel^T ; R = in@Wroot^T + b --------------
// lane = out channel; W in VGPRs; one readlane feeds both matrices.
// NOTE: `in` and `R` may alias (in-place per-row rewrite) -> no restrict.
__global__ __launch_bounds__(256) void k_xform(const float* in,
                                               const float* __restrict__ Wrel,
                                               const float* __restrict__ Wroot,
                                               const float* __restrict__ bias,
                                               float* __restrict__ Y,
                                               float* R, int n)
{
    int lane = threadIdx.x & 63;
    float4 wrel[16], wroot[16];
    const float4* Wr = (const float4*)(Wrel + lane * CH);
    const float4* Wt = (const float4*)(Wroot + lane * CH);
#pragma unroll
    for (int i = 0; i < 16; ++i) { wrel[i] = Wr[i]; wroot[i] = Wt[i]; }
    float bv = bias[lane];

    int wid = blockIdx.x * 4 + (threadIdx.x >> 6);
    int nw = gridDim.x * 4;
    for (int n0 = wid * 2; n0 < n; n0 += nw * 2) {
        int n1 = n0 + 1;
        bool two = (n1 < n);
        float xv0 = in[(size_t)n0 * CH + lane];
        float xv1 = two ? in[(size_t)n1 * CH + lane] : 0.f;
        float y0a = 0.f, y0b = 0.f, r0a = 0.f, r0b = 0.f;
        float y1a = 0.f, y1b = 0.f, r1a = 0.f, r1b = 0.f;
#pragma unroll
        for (int i = 0; i < 16; ++i) {
            float4 wr = wrel[i], wt = wroot[i];
            float a0 = rlane(xv0, 4 * i + 0), a1 = rlane(xv1, 4 * i + 0);
            y0a += a0 * wr.x; r0a += a0 * wt.x; y1a += a1 * wr.x; r1a += a1 * wt.x;
            float b0 = rlane(xv0, 4 * i + 1), b1 = rlane(xv1, 4 * i + 1);
            y0b += b0 * wr.y; r0b += b0 * wt.y; y1b += b1 * wr.y; r1b += b1 * wt.y;
            float c0 = rlane(xv0, 4 * i + 2), c1 = rlane(xv1, 4 * i + 2);
            y0a += c0 * wr.z; r0a += c0 * wt.z; y1a += c1 * wr.z; r1a += c1 * wt.z;
            float d0 = rlane(xv0, 4 * i + 3), d1 = rlane(xv1, 4 * i + 3);
            y0b += d0 * wr.w; r0b += d0 * wt.w; y1b += d1 * wr.w; r1b += d1 * wt.w;
        }
        Y[(size_t)n0 * CH + lane] = y0a + y0b;
        R[(size_t)n0 * CH + lane] = r0a + r0b + bv;
        if (two) {
            Y[(size_t)n1 * CH + lane] = y1a + y1b;
            R[(size_t)n1 * CH + lane] = r1a + r1b + bv;
        }
    }
}

// -------- pure gather: h[node] = relu(sum_{src} Y[src] + RO[node]) ---------
// 16 lanes per row (float4), 4 rows per load instr, 16 rows in flight.
// RO is read then overwritten in place by the owning wave.
__global__ __launch_bounds__(256) void k_gather_relu(const float* __restrict__ Y,
                                                     const int* __restrict__ rowptr,
                                                     const int* __restrict__ csr,
                                                     float* __restrict__ RO, int n)
{
    int lane = threadIdx.x & 63;
    int grp = lane >> 4, sub = lane & 15;
    int wid = blockIdx.x * 4 + (threadIdx.x >> 6);
    int nw = gridDim.x * 4;
    for (int node = wid; node < n; node += nw) {
        int e0 = rowptr[node], e1 = rowptr[node + 1];
        float4 a0 = make_float4(0, 0, 0, 0), a1 = a0, a2 = a0, a3 = a0;
        int e = e0;
        for (; e + 16 <= e1; e += 16) {
            int s0 = csr[e + grp],      s1 = csr[e + 4 + grp];
            int s2 = csr[e + 8 + grp],  s3 = csr[e + 12 + grp];
            float4 v0 = *(const float4*)(Y + (size_t)s0 * CH + sub * 4);
            float4 v1 = *(const float4*)(Y + (size_t)s1 * CH + sub * 4);
            float4 v2 = *(const float4*)(Y + (size_t)s2 * CH + sub * 4);
            float4 v3 = *(const float4*)(Y + (size_t)s3 * CH + sub * 4);
            f4add(a0, v0); f4add(a1, v1); f4add(a2, v2); f4add(a3, v3);
        }
        for (; e + 4 <= e1; e += 4) {
            int s = csr[e + grp];
            f4add(a0, *(const float4*)(Y + (size_t)s * CH + sub * 4));
        }
        if (e + grp < e1) {
            int s = csr[e + grp];
            f4add(a1, *(const float4*)(Y + (size_t)s * CH + sub * 4));
        }
        f4add(a0, a1); f4add(a2, a3); f4add(a0, a2);
        a0.x += __shfl_xor(a0.x, 16); a0.y += __shfl_xor(a0.y, 16);
        a0.z += __shfl_xor(a0.z, 16); a0.w += __shfl_xor(a0.w, 16);
        a0.x += __shfl_xor(a0.x, 32); a0.y += __shfl_xor(a0.y, 32);
        a0.z += __shfl_xor(a0.z, 32); a0.w += __shfl_xor(a0.w, 32);
        if (grp == 0) {
            const float4 r = *(const float4*)(RO + (size_t)node * CH + sub * 4);
            float4 h;
            h.x = fmaxf(a0.x + r.x, 0.f); h.y = fmaxf(a0.y + r.y, 0.f);
            h.z = fmaxf(a0.z + r.z, 0.f); h.w = fmaxf(a0.w + r.w, 0.f);
            *(float4*)(RO + (size_t)node * CH + sub * 4) = h;
        }
    }
}

// -------- gather + relu + mean-pool accumulate (layer 2) -------------------
__global__ __launch_bounds__(256) void k_gather_pool(const float* __restrict__ Y,
                                                     const float* __restrict__ R,
                                                     const int* __restrict__ rowptr,
                                                     const int* __restrict__ csr,
                                                     const int* __restrict__ batch,
                                                     float* __restrict__ sums,
                                                     int n, int chunk)
{
    int lane = threadIdx.x & 63;
    int grp = lane >> 4, sub = lane & 15;
    int wid = blockIdx.x * 4 + (threadIdx.x >> 6);
    int nb = wid * chunk, ne = min(nb + chunk, n);
    float4 run = make_float4(0, 0, 0, 0);
    int gcur = -1;
    for (int node = nb; node < ne; ++node) {
        int e0 = rowptr[node], e1 = rowptr[node + 1];
        float4 a0 = make_float4(0, 0, 0, 0), a1 = a0, a2 = a0, a3 = a0;
        int e = e0;
        for (; e + 16 <= e1; e += 16) {
            int s0 = csr[e + grp],      s1 = csr[e + 4 + grp];
            int s2 = csr[e + 8 + grp],  s3 = csr[e + 12 + grp];
            float4 v0 = *(const float4*)(Y + (size_t)s0 * CH + sub * 4);
            float4 v1 = *(const float4*)(Y + (size_t)s1 * CH + sub * 4);
            float4 v2 = *(const float4*)(Y + (size_t)s2 * CH + sub * 4);
            float4 v3 = *(const float4*)(Y + (size_t)s3 * CH + sub * 4);
            f4add(a0, v0); f4add(a1, v1); f4add(a2, v2); f4add(a3, v3);
        }
        for (; e + 4 <= e1; e += 4) {
            int s = csr[e + grp];
            f4add(a0, *(const float4*)(Y + (size_t)s * CH + sub * 4));
        }
        if (e + grp < e1) {
            int s = csr[e + grp];
            f4add(a1, *(const float4*)(Y + (size_t)s * CH + sub * 4));
        }
        f4add(a0, a1); f4add(a2, a3); f4add(a0, a2);
        a0.x += __shfl_xor(a0.x, 16); a0.y += __shfl_xor(a0.y, 16);
        a0.z += __shfl_xor(a0.z, 16); a0.w += __shfl_xor(a0.w, 16);
        a0.x += __shfl_xor(a0.x, 32); a0.y += __shfl_xor(a0.y, 32);
        a0.z += __shfl_xor(a0.z, 32); a0.w += __shfl_xor(a0.w, 32);
        if (grp == 0) {
            const float4 r = *(const float4*)(R + (size_t)node * CH + sub * 4);
            float4 h;
            h.x = fmaxf(a0.x + r.x, 0.f); h.y = fmaxf(a0.y + r.y, 0.f);
            h.z = fmaxf(a0.z + r.z, 0.f); h.w = fmaxf(a0.w + r.w, 0.f);
            int g = batch[node];
            if (g != gcur) {
                if (gcur >= 0) {
                    atomicAdd(&sums[gcur * CH + sub * 4 + 0], run.x);
                    atomicAdd(&sums[gcur * CH + sub * 4 + 1], run.y);
                    atomicAdd(&sums[gcur * CH + sub * 4 + 2], run.z);
                    atomicAdd(&sums[gcur * CH + sub * 4 + 3], run.w);
                }
                run = make_float4(0, 0, 0, 0);
                gcur = g;
            }
            f4add(run, h);
        }
    }
    if (grp == 0 && gcur >= 0) {
        atomicAdd(&sums[gcur * CH + sub * 4 + 0], run.x);
        atomicAdd(&sums[gcur * CH + sub * 4 + 1], run.y);
        atomicAdd(&sums[gcur * CH + sub * 4 + 2], run.z);
        atomicAdd(&sums[gcur * CH + sub * 4 + 3], run.w);
    }
}

// -------- final head --------------------------------------------------------
__global__ void k_final(const float* __restrict__ sums,
                        const int* __restrict__ batch,
                        const float* __restrict__ Wlin,
                        const float* __restrict__ blin,
                        float* __restrict__ out, int n_nodes)
{
    int t = threadIdx.x;
    if (t >= NG * NC) return;
    int g = t / NC, c = t % NC;
    int lo = 0, hi = n_nodes;
    while (lo < hi) { int mid = (lo + hi) >> 1; if (batch[mid] < g) lo = mid + 1; else hi = mid; }
    int lb = lo;
    lo = 0; hi = n_nodes;
    while (lo < hi) { int mid = (lo + hi) >> 1; if (batch[mid] < g + 1) lo = mid + 1; else hi = mid; }
    int cnt = lo - lb;
    float inv = 1.0f / fmaxf((float)cnt, 1.0f);
    float acc = blin[c];
    for (int k = 0; k < CH; ++k)
        acc += sums[g * CH + k] * inv * Wlin[c * CH + k];
    out[g * NC + c] = acc;
}

extern "C" void kernel_launch(void* const* d_in, const int* in_sizes, int n_in,
                              void* d_out, int out_size, void* d_ws, size_t ws_size,
                              hipStream_t stream)
{
    const float* x      = (const float*)d_in[0];
    const int*   ei     = (const int*)d_in[1];
    const int*   batch  = (const int*)d_in[2];
    const float* W1rel  = (const float*)d_in[3];
    const float* W1root = (const float*)d_in[4];
    const float* b1     = (const float*)d_in[5];
    const float* W2rel  = (const float*)d_in[6];
    const float* W2root = (const float*)d_in[7];
    const float* b2     = (const float*)d_in[8];
    const float* Wlin   = (const float*)d_in[9];
    const float* blin   = (const float*)d_in[10];
    float* out = (float*)d_out;

    int n_nodes = in_sizes[0] / CH;
    int n_edges = in_sizes[1] / 2;
    const int* src = ei;
    const int* dst = ei + n_edges;

    // workspace (~58.5 MB): Y | H (R1/h1/R2 in place) | rowptr | cursor | csr | sums
    float* Y      = (float*)d_ws;
    float* H      = Y + (size_t)n_nodes * CH;
    int*   rowptr = (int*)(H + (size_t)n_nodes * CH);
    int*   cursor = rowptr + (n_nodes + 1);
    int*   csr    = cursor + n_nodes;
    float* sums   = (float*)(csr + n_edges);

    int eb = (n_edges + 255) / 256;

    // ---- build CSR (dst -> srcs) ----
    hipMemsetAsync(cursor, 0, n_nodes * sizeof(int), stream);
    k_deg<<<eb, 256, 0, stream>>>(dst, cursor, n_edges);
    k_scan<<<1, 1024, 0, stream>>>(cursor, rowptr, n_nodes);
    k_fill<<<eb, 256, 0, stream>>>(src, dst, cursor, csr, n_edges);

    // ---- layer 1 ----
    k_xform<<<2048, 256, 0, stream>>>(x, W1rel, W1root, b1, Y, H, n_nodes);
    k_gather_relu<<<2048, 256, 0, stream>>>(Y, rowptr, csr, H, n_nodes);

    // ---- layer 2 ----
    k_xform<<<2048, 256, 0, stream>>>(H, W2rel, W2root, b2, Y, H, n_nodes);
    hipMemsetAsync(sums, 0, NG * CH * sizeof(float), stream);
    int waves = 2048 * 4;
    int chunk = (n_nodes + waves - 1) / waves;
    k_gather_pool<<<2048, 256, 0, stream>>>(Y, H, rowptr, csr, batch, sums, n_nodes, chunk);

    // ---- head ----
    k_final<<<1, NG * NC, 0, stream>>>(sums, batch, Wlin, blin, out, n_nodes);
}

// Round 4
// 453.224 us; speedup vs baseline: 6.8005x; 1.4886x over previous
//
#include <hip/hip_runtime.h>

constexpr int CH = 64;      // IN_CH == HID == 64
constexpr int NG = 64;      // graphs
constexpr int NC = 10;      // classes

__device__ __forceinline__ float rlane(float v, int l) {
    return __int_as_float(__builtin_amdgcn_readlane(__float_as_int(v), l));
}
__device__ __forceinline__ void f4add(float4& a, const float4 v) {
    a.x += v.x; a.y += v.y; a.z += v.z; a.w += v.w;
}

// ---------------- CSR build ------------------------------------------------
__global__ __launch_bounds__(256) void k_deg(const int* __restrict__ dst,
                                             int* __restrict__ deg, int n_edges)
{
    int e = blockIdx.x * 256 + threadIdx.x;
    if (e < n_edges) atomicAdd(&deg[dst[e]], 1);
}

// ---- hierarchical exclusive scan: A (block sums) / B (scan partials) / C --
__global__ __launch_bounds__(256) void k_scanA(const int* __restrict__ deg,
                                               int* __restrict__ partials, int n)
{
    __shared__ int lds[256];
    int base = blockIdx.x * 1024 + threadIdx.x * 4;
    int s = 0;
#pragma unroll
    for (int j = 0; j < 4; ++j) { int i = base + j; if (i < n) s += deg[i]; }
    lds[threadIdx.x] = s;
    __syncthreads();
    for (int off = 128; off > 0; off >>= 1) {
        if (threadIdx.x < off) lds[threadIdx.x] += lds[threadIdx.x + off];
        __syncthreads();
    }
    if (threadIdx.x == 0) partials[blockIdx.x] = lds[0];
}

// single block; nb <= 1024. Converts partials to exclusive offsets, writes total.
__global__ __launch_bounds__(1024) void k_scanB(int* __restrict__ partials,
                                                int* __restrict__ rowptr,
                                                int n, int nb)
{
    __shared__ int lds[1024];
    int t = threadIdx.x;
    int v = (t < nb) ? partials[t] : 0;
    lds[t] = v;
    __syncthreads();
    for (int off = 1; off < 1024; off <<= 1) {
        int u = (t >= off) ? lds[t - off] : 0;
        __syncthreads();
        lds[t] += u;
        __syncthreads();
    }
    if (t < nb) partials[t] = lds[t] - v;        // exclusive
    if (t == nb - 1) rowptr[n] = lds[t];         // grand total
}

// re-read degrees, block-local exclusive scan + global offset, emit rowptr+cursor
__global__ __launch_bounds__(256) void k_scanC(int* deg_cursor,
                                               const int* __restrict__ partials,
                                               int* __restrict__ rowptr, int n)
{
    __shared__ int lds[256];
    int base = blockIdx.x * 1024 + threadIdx.x * 4;
    int d0 = 0, d1 = 0, d2 = 0, d3 = 0;
    if (base + 0 < n) d0 = deg_cursor[base + 0];
    if (base + 1 < n) d1 = deg_cursor[base + 1];
    if (base + 2 < n) d2 = deg_cursor[base + 2];
    if (base + 3 < n) d3 = deg_cursor[base + 3];
    int s = d0 + d1 + d2 + d3;
    lds[threadIdx.x] = s;
    __syncthreads();
    for (int off = 1; off < 256; off <<= 1) {
        int u = (threadIdx.x >= off) ? lds[threadIdx.x - off] : 0;
        __syncthreads();
        lds[threadIdx.x] += u;
        __syncthreads();
    }
    int run = partials[blockIdx.x] + lds[threadIdx.x] - s;   // exclusive start
    if (base + 0 < n) { rowptr[base + 0] = run; deg_cursor[base + 0] = run; run += d0; }
    if (base + 1 < n) { rowptr[base + 1] = run; deg_cursor[base + 1] = run; run += d1; }
    if (base + 2 < n) { rowptr[base + 2] = run; deg_cursor[base + 2] = run; run += d2; }
    if (base + 3 < n) { rowptr[base + 3] = run; deg_cursor[base + 3] = run; run += d3; }
}

__global__ __launch_bounds__(256) void k_fill(const int* __restrict__ src,
                                              const int* __restrict__ dst,
                                              int* __restrict__ cursor,
                                              int* __restrict__ csr, int n_edges)
{
    int e = blockIdx.x * 256 + threadIdx.x;
    if (e >= n_edges) return;
    int pos = atomicAdd(&cursor[dst[e]], 1);
    csr[pos] = src[e];
}

// -------- streaming dense: Y = in@Wrel^T ; R = in@Wroot^T + b --------------
// lane = out channel; W in VGPRs; one readlane feeds both matrices.
// NOTE: `in` and `R` may alias (in-place per-row rewrite) -> no restrict.
__global__ __launch_bounds__(256) void k_xform(const float* in,
                                               const float* __restrict__ Wrel,
                                               const float* __restrict__ Wroot,
                                               const float* __restrict__ bias,
                                               float* __restrict__ Y,
                                               float* R, int n)
{
    int lane = threadIdx.x & 63;
    float4 wrel[16], wroot[16];
    const float4* Wr = (const float4*)(Wrel + lane * CH);
    const float4* Wt = (const float4*)(Wroot + lane * CH);
#pragma unroll
    for (int i = 0; i < 16; ++i) { wrel[i] = Wr[i]; wroot[i] = Wt[i]; }
    float bv = bias[lane];

    int wid = blockIdx.x * 4 + (threadIdx.x >> 6);
    int nw = gridDim.x * 4;
    for (int n0 = wid * 2; n0 < n; n0 += nw * 2) {
        int n1 = n0 + 1;
        bool two = (n1 < n);
        float xv0 = in[(size_t)n0 * CH + lane];
        float xv1 = two ? in[(size_t)n1 * CH + lane] : 0.f;
        float y0a = 0.f, y0b = 0.f, r0a = 0.f, r0b = 0.f;
        float y1a = 0.f, y1b = 0.f, r1a = 0.f, r1b = 0.f;
#pragma unroll
        for (int i = 0; i < 16; ++i) {
            float4 wr = wrel[i], wt = wroot[i];
            float a0 = rlane(xv0, 4 * i + 0), a1 = rlane(xv1, 4 * i + 0);
            y0a += a0 * wr.x; r0a += a0 * wt.x; y1a += a1 * wr.x; r1a += a1 * wt.x;
            float b0 = rlane(xv0, 4 * i + 1), b1 = rlane(xv1, 4 * i + 1);
            y0b += b0 * wr.y; r0b += b0 * wt.y; y1b += b1 * wr.y; r1b += b1 * wt.y;
            float c0 = rlane(xv0, 4 * i + 2), c1 = rlane(xv1, 4 * i + 2);
            y0a += c0 * wr.z; r0a += c0 * wt.z; y1a += c1 * wr.z; r1a += c1 * wt.z;
            float d0 = rlane(xv0, 4 * i + 3), d1 = rlane(xv1, 4 * i + 3);
            y0b += d0 * wr.w; r0b += d0 * wt.w; y1b += d1 * wr.w; r1b += d1 * wt.w;
        }
        Y[(size_t)n0 * CH + lane] = y0a + y0b;
        R[(size_t)n0 * CH + lane] = r0a + r0b + bv;
        if (two) {
            Y[(size_t)n1 * CH + lane] = y1a + y1b;
            R[(size_t)n1 * CH + lane] = r1a + r1b + bv;
        }
    }
}

// -------- pure gather: h[node] = relu(sum_{src} Y[src] + RO[node]) ---------
// 16 lanes per row (float4), 4 rows per load instr, 16 rows in flight.
// RO is read then overwritten in place by the owning wave.
__global__ __launch_bounds__(256) void k_gather_relu(const float* __restrict__ Y,
                                                     const int* __restrict__ rowptr,
                                                     const int* __restrict__ csr,
                                                     float* __restrict__ RO, int n)
{
    int lane = threadIdx.x & 63;
    int grp = lane >> 4, sub = lane & 15;
    int wid = blockIdx.x * 4 + (threadIdx.x >> 6);
    int nw = gridDim.x * 4;
    for (int node = wid; node < n; node += nw) {
        int e0 = rowptr[node], e1 = rowptr[node + 1];
        float4 a0 = make_float4(0, 0, 0, 0), a1 = a0, a2 = a0, a3 = a0;
        int e = e0;
        for (; e + 16 <= e1; e += 16) {
            int s0 = csr[e + grp],      s1 = csr[e + 4 + grp];
            int s2 = csr[e + 8 + grp],  s3 = csr[e + 12 + grp];
            float4 v0 = *(const float4*)(Y + (size_t)s0 * CH + sub * 4);
            float4 v1 = *(const float4*)(Y + (size_t)s1 * CH + sub * 4);
            float4 v2 = *(const float4*)(Y + (size_t)s2 * CH + sub * 4);
            float4 v3 = *(const float4*)(Y + (size_t)s3 * CH + sub * 4);
            f4add(a0, v0); f4add(a1, v1); f4add(a2, v2); f4add(a3, v3);
        }
        for (; e + 4 <= e1; e += 4) {
            int s = csr[e + grp];
            f4add(a0, *(const float4*)(Y + (size_t)s * CH + sub * 4));
        }
        if (e + grp < e1) {
            int s = csr[e + grp];
            f4add(a1, *(const float4*)(Y + (size_t)s * CH + sub * 4));
        }
        f4add(a0, a1); f4add(a2, a3); f4add(a0, a2);
        a0.x += __shfl_xor(a0.x, 16); a0.y += __shfl_xor(a0.y, 16);
        a0.z += __shfl_xor(a0.z, 16); a0.w += __shfl_xor(a0.w, 16);
        a0.x += __shfl_xor(a0.x, 32); a0.y += __shfl_xor(a0.y, 32);
        a0.z += __shfl_xor(a0.z, 32); a0.w += __shfl_xor(a0.w, 32);
        if (grp == 0) {
            const float4 r = *(const float4*)(RO + (size_t)node * CH + sub * 4);
            float4 h;
            h.x = fmaxf(a0.x + r.x, 0.f); h.y = fmaxf(a0.y + r.y, 0.f);
            h.z = fmaxf(a0.z + r.z, 0.f); h.w = fmaxf(a0.w + r.w, 0.f);
            *(float4*)(RO + (size_t)node * CH + sub * 4) = h;
        }
    }
}

// -------- gather + relu + mean-pool accumulate (layer 2) -------------------
__global__ __launch_bounds__(256) void k_gather_pool(const float* __restrict__ Y,
                                                     const float* __restrict__ R,
                                                     const int* __restrict__ rowptr,
                                                     const int* __restrict__ csr,
                                                     const int* __restrict__ batch,
                                                     float* __restrict__ sums,
                                                     int n, int chunk)
{
    int lane = threadIdx.x & 63;
    int grp = lane >> 4, sub = lane & 15;
    int wid = blockIdx.x * 4 + (threadIdx.x >> 6);
    int nb = wid * chunk, ne = min(nb + chunk, n);
    float4 run = make_float4(0, 0, 0, 0);
    int gcur = -1;
    for (int node = nb; node < ne; ++node) {
        int e0 = rowptr[node], e1 = rowptr[node + 1];
        float4 a0 = make_float4(0, 0, 0, 0), a1 = a0, a2 = a0, a3 = a0;
        int e = e0;
        for (; e + 16 <= e1; e += 16) {
            int s0 = csr[e + grp],      s1 = csr[e + 4 + grp];
            int s2 = csr[e + 8 + grp],  s3 = csr[e + 12 + grp];
            float4 v0 = *(const float4*)(Y + (size_t)s0 * CH + sub * 4);
            float4 v1 = *(const float4*)(Y + (size_t)s1 * CH + sub * 4);
            float4 v2 = *(const float4*)(Y + (size_t)s2 * CH + sub * 4);
            float4 v3 = *(const float4*)(Y + (size_t)s3 * CH + sub * 4);
            f4add(a0, v0); f4add(a1, v1); f4add(a2, v2); f4add(a3, v3);
        }
        for (; e + 4 <= e1; e += 4) {
            int s = csr[e + grp];
            f4add(a0, *(const float4*)(Y + (size_t)s * CH + sub * 4));
        }
        if (e + grp < e1) {
            int s = csr[e + grp];
            f4add(a1, *(const float4*)(Y + (size_t)s * CH + sub * 4));
        }
        f4add(a0, a1); f4add(a2, a3); f4add(a0, a2);
        a0.x += __shfl_xor(a0.x, 16); a0.y += __shfl_xor(a0.y, 16);
        a0.z += __shfl_xor(a0.z, 16); a0.w += __shfl_xor(a0.w, 16);
        a0.x += __shfl_xor(a0.x, 32); a0.y += __shfl_xor(a0.y, 32);
        a0.z += __shfl_xor(a0.z, 32); a0.w += __shfl_xor(a0.w, 32);
        if (grp == 0) {
            const float4 r = *(const float4*)(R + (size_t)node * CH + sub * 4);
            float4 h;
            h.x = fmaxf(a0.x + r.x, 0.f); h.y = fmaxf(a0.y + r.y, 0.f);
            h.z = fmaxf(a0.z + r.z, 0.f); h.w = fmaxf(a0.w + r.w, 0.f);
            int g = batch[node];
            if (g != gcur) {
                if (gcur >= 0) {
                    atomicAdd(&sums[gcur * CH + sub * 4 + 0], run.x);
                    atomicAdd(&sums[gcur * CH + sub * 4 + 1], run.y);
                    atomicAdd(&sums[gcur * CH + sub * 4 + 2], run.z);
                    atomicAdd(&sums[gcur * CH + sub * 4 + 3], run.w);
                }
                run = make_float4(0, 0, 0, 0);
                gcur = g;
            }
            f4add(run, h);
        }
    }
    if (grp == 0 && gcur >= 0) {
        atomicAdd(&sums[gcur * CH + sub * 4 + 0], run.x);
        atomicAdd(&sums[gcur * CH + sub * 4 + 1], run.y);
        atomicAdd(&sums[gcur * CH + sub * 4 + 2], run.z);
        atomicAdd(&sums[gcur * CH + sub * 4 + 3], run.w);
    }
}

// -------- final head --------------------------------------------------------
__global__ void k_final(const float* __restrict__ sums,
                        const int* __restrict__ batch,
                        const float* __restrict__ Wlin,
                        const float* __restrict__ blin,
                        float* __restrict__ out, int n_nodes)
{
    int t = threadIdx.x;
    if (t >= NG * NC) return;
    int g = t / NC, c = t % NC;
    int lo = 0, hi = n_nodes;
    while (lo < hi) { int mid = (lo + hi) >> 1; if (batch[mid] < g) lo = mid + 1; else hi = mid; }
    int lb = lo;
    lo = 0; hi = n_nodes;
    while (lo < hi) { int mid = (lo + hi) >> 1; if (batch[mid] < g + 1) lo = mid + 1; else hi = mid; }
    int cnt = lo - lb;
    float inv = 1.0f / fmaxf((float)cnt, 1.0f);
    float acc = blin[c];
    for (int k = 0; k < CH; ++k)
        acc += sums[g * CH + k] * inv * Wlin[c * CH + k];
    out[g * NC + c] = acc;
}

extern "C" void kernel_launch(void* const* d_in, const int* in_sizes, int n_in,
                              void* d_out, int out_size, void* d_ws, size_t ws_size,
                              hipStream_t stream)
{
    const float* x      = (const float*)d_in[0];
    const int*   ei     = (const int*)d_in[1];
    const int*   batch  = (const int*)d_in[2];
    const float* W1rel  = (const float*)d_in[3];
    const float* W1root = (const float*)d_in[4];
    const float* b1     = (const float*)d_in[5];
    const float* W2rel  = (const float*)d_in[6];
    const float* W2root = (const float*)d_in[7];
    const float* b2     = (const float*)d_in[8];
    const float* Wlin   = (const float*)d_in[9];
    const float* blin   = (const float*)d_in[10];
    float* out = (float*)d_out;

    int n_nodes = in_sizes[0] / CH;
    int n_edges = in_sizes[1] / 2;
    const int* src = ei;
    const int* dst = ei + n_edges;

    // workspace: Y | H (R1/h1/R2 in place) | rowptr | cursor | csr | sums | partials
    float* Y        = (float*)d_ws;
    float* H        = Y + (size_t)n_nodes * CH;
    int*   rowptr   = (int*)(H + (size_t)n_nodes * CH);
    int*   cursor   = rowptr + (n_nodes + 1);
    int*   csr      = cursor + n_nodes;
    float* sums     = (float*)(csr + n_edges);
    int*   partials = (int*)(sums + NG * CH);

    int eb = (n_edges + 255) / 256;
    int nb = (n_nodes + 1023) / 1024;    // scan blocks (1024 elems each)

    // ---- build CSR (dst -> srcs) ----
    hipMemsetAsync(cursor, 0, n_nodes * sizeof(int), stream);
    k_deg<<<eb, 256, 0, stream>>>(dst, cursor, n_edges);
    k_scanA<<<nb, 256, 0, stream>>>(cursor, partials, n_nodes);
    k_scanB<<<1, 1024, 0, stream>>>(partials, rowptr, n_nodes, nb);
    k_scanC<<<nb, 256, 0, stream>>>(cursor, partials, rowptr, n_nodes);
    k_fill<<<eb, 256, 0, stream>>>(src, dst, cursor, csr, n_edges);

    // ---- layer 1 ----
    k_xform<<<2048, 256, 0, stream>>>(x, W1rel, W1root, b1, Y, H, n_nodes);
    k_gather_relu<<<2048, 256, 0, stream>>>(Y, rowptr, csr, H, n_nodes);

    // ---- layer 2 ----
    k_xform<<<2048, 256, 0, stream>>>(H, W2rel, W2root, b2, Y, H, n_nodes);
    hipMemsetAsync(sums, 0, NG * CH * sizeof(float), stream);
    int waves = 2048 * 4;
    int chunk = (n_nodes + waves - 1) / waves;
    k_gather_pool<<<2048, 256, 0, stream>>>(Y, H, rowptr, csr, batch, sums, n_nodes, chunk);

    // ---- head ----
    k_final<<<1, NG * NC, 0, stream>>>(sums, batch, Wlin, blin, out, n_nodes);
}

// Round 5
// 286.094 us; speedup vs baseline: 10.7733x; 1.5842x over previous
//
#include <hip/hip_runtime.h>

constexpr int CH = 64;      // IN_CH == HID == 64
constexpr int NG = 64;      // graphs
constexpr int NC = 10;      // classes
constexpr int SHIFT = 9;    // bucket = 512 nodes
constexpr int BW = 1 << SHIFT;
constexpr int EPW = 8192;   // edges per workgroup in bucket pass

__device__ __forceinline__ float rlane(float v, int l) {
    return __int_as_float(__builtin_amdgcn_readlane(__float_as_int(v), l));
}
__device__ __forceinline__ void f4add(float4& a, const float4 v) {
    a.x += v.x; a.y += v.y; a.z += v.z; a.w += v.w;
}
__device__ __forceinline__ unsigned short f2bf(float f) {   // RNE f32->bf16
    unsigned u = __float_as_uint(f);
    u = (u + 0x7FFFu + ((u >> 16) & 1u)) >> 16;
    return (unsigned short)u;
}
__device__ __forceinline__ void bfacc(float4& a, unsigned lo, unsigned hi) {
    a.x += __uint_as_float(lo << 16);
    a.y += __uint_as_float(lo & 0xFFFF0000u);
    a.z += __uint_as_float(hi << 16);
    a.w += __uint_as_float(hi & 0xFFFF0000u);
}

// ---- B1: bin edges by dst bucket; packed record = src | (dstLocal<<17) ----
__global__ __launch_bounds__(256) void k_bucket(const int* __restrict__ src,
                                                const int* __restrict__ dst,
                                                int* __restrict__ bcnt,
                                                int* __restrict__ bbuf,
                                                int nb, int cap, int n_edges)
{
    __shared__ int hist[256];
    __shared__ int cur[256];
    int t = threadIdx.x;
    int e0 = blockIdx.x * EPW;
    int e1 = min(e0 + EPW, n_edges);
    if (t < nb) hist[t] = 0;
    __syncthreads();
    for (int e = e0 + t; e < e1; e += 256)
        atomicAdd(&hist[dst[e] >> SHIFT], 1);
    __syncthreads();
    if (t < nb) cur[t] = atomicAdd(&bcnt[t], hist[t]);   // reserve range
    __syncthreads();
    for (int e = e0 + t; e < e1; e += 256) {
        int d = dst[e];
        int b = d >> SHIFT;
        int pos = atomicAdd(&cur[b], 1);
        if (pos < cap)
            bbuf[(size_t)b * cap + pos] = src[e] | ((d & (BW - 1)) << 17);
    }
}

// ---- scan bucket counts -> bucket csr bases; also rowptr[n] ----------------
__global__ __launch_bounds__(256) void k_bscan(const int* __restrict__ bcnt,
                                               int* __restrict__ bbase,
                                               int* __restrict__ rowptr,
                                               int nb, int n, int cap)
{
    __shared__ int lds[256];
    int t = threadIdx.x;
    int v = (t < nb) ? min(bcnt[t], cap) : 0;
    lds[t] = v;
    __syncthreads();
    for (int off = 1; off < 256; off <<= 1) {
        int u = (t >= off) ? lds[t - off] : 0;
        __syncthreads();
        lds[t] += u;
        __syncthreads();
    }
    if (t < nb) bbase[t] = lds[t] - v;
    if (t == nb - 1) { bbase[nb] = lds[t]; rowptr[n] = lds[t]; }
}

// ---- B2: per-bucket local count + scan + place; contiguous csr window -----
__global__ __launch_bounds__(256) void k_build(const int* __restrict__ bbuf,
                                               const int* __restrict__ bcnt,
                                               const int* __restrict__ bbase,
                                               int* __restrict__ rowptr,
                                               int* __restrict__ csr,
                                               int cap, int n)
{
    __shared__ int hist[BW];
    __shared__ int cur[BW];
    __shared__ int psum[256];
    int b = blockIdx.x;
    int t = threadIdx.x;
    int cnt = min(bcnt[b], cap);
    int base = bbase[b];
    const int* mybuf = bbuf + (size_t)b * cap;
    hist[t] = 0; hist[t + 256] = 0;
    __syncthreads();
    for (int i = t; i < cnt; i += 256)
        atomicAdd(&hist[mybuf[i] >> 17], 1);
    __syncthreads();
    int h0 = hist[2 * t], h1 = hist[2 * t + 1];
    int ps = h0 + h1;
    psum[t] = ps;
    __syncthreads();
    for (int off = 1; off < 256; off <<= 1) {
        int u = (t >= off) ? psum[t - off] : 0;
        __syncthreads();
        psum[t] += u;
        __syncthreads();
    }
    int e0 = psum[t] - ps;                 // exclusive start of pair (2t,2t+1)
    int nodeBase = b * BW;
    cur[2 * t]     = base + e0;
    cur[2 * t + 1] = base + e0 + h0;
    if (nodeBase + 2 * t < n)     rowptr[nodeBase + 2 * t]     = base + e0;
    if (nodeBase + 2 * t + 1 < n) rowptr[nodeBase + 2 * t + 1] = base + e0 + h0;
    __syncthreads();
    for (int i = t; i < cnt; i += 256) {
        int v = mybuf[i];
        int pos = atomicAdd(&cur[v >> 17], 1);
        csr[pos] = v & 0x1FFFF;
    }
}

// -------- streaming dense: Ybf16 = in@Wrel^T ; R = in@Wroot^T + b ----------
// NOTE: `in` and `R` may alias (in-place per-row rewrite) -> no restrict.
__global__ __launch_bounds__(256) void k_xform(const float* in,
                                               const float* __restrict__ Wrel,
                                               const float* __restrict__ Wroot,
                                               const float* __restrict__ bias,
                                               unsigned short* __restrict__ Y,
                                               float* R, int n)
{
    int lane = threadIdx.x & 63;
    float4 wrel[16], wroot[16];
    const float4* Wr = (const float4*)(Wrel + lane * CH);
    const float4* Wt = (const float4*)(Wroot + lane * CH);
#pragma unroll
    for (int i = 0; i < 16; ++i) { wrel[i] = Wr[i]; wroot[i] = Wt[i]; }
    float bv = bias[lane];

    int wid = blockIdx.x * 4 + (threadIdx.x >> 6);
    int nw = gridDim.x * 4;
    for (int n0 = wid * 2; n0 < n; n0 += nw * 2) {
        int n1 = n0 + 1;
        bool two = (n1 < n);
        float xv0 = in[(size_t)n0 * CH + lane];
        float xv1 = two ? in[(size_t)n1 * CH + lane] : 0.f;
        float y0a = 0.f, y0b = 0.f, r0a = 0.f, r0b = 0.f;
        float y1a = 0.f, y1b = 0.f, r1a = 0.f, r1b = 0.f;
#pragma unroll
        for (int i = 0; i < 16; ++i) {
            float4 wr = wrel[i], wt = wroot[i];
            float a0 = rlane(xv0, 4 * i + 0), a1 = rlane(xv1, 4 * i + 0);
            y0a += a0 * wr.x; r0a += a0 * wt.x; y1a += a1 * wr.x; r1a += a1 * wt.x;
            float b0 = rlane(xv0, 4 * i + 1), b1 = rlane(xv1, 4 * i + 1);
            y0b += b0 * wr.y; r0b += b0 * wt.y; y1b += b1 * wr.y; r1b += b1 * wt.y;
            float c0 = rlane(xv0, 4 * i + 2), c1 = rlane(xv1, 4 * i + 2);
            y0a += c0 * wr.z; r0a += c0 * wt.z; y1a += c1 * wr.z; r1a += c1 * wt.z;
            float d0 = rlane(xv0, 4 * i + 3), d1 = rlane(xv1, 4 * i + 3);
            y0b += d0 * wr.w; r0b += d0 * wt.w; y1b += d1 * wr.w; r1b += d1 * wt.w;
        }
        Y[(size_t)n0 * CH + lane] = f2bf(y0a + y0b);
        R[(size_t)n0 * CH + lane] = r0a + r0b + bv;
        if (two) {
            Y[(size_t)n1 * CH + lane] = f2bf(y1a + y1b);
            R[(size_t)n1 * CH + lane] = r1a + r1b + bv;
        }
    }
}

// -------- pure gather (bf16 rows): h[node] = relu(sum Y[src] + RO[node]) ---
// 16 lanes per row (uint2 = 4 bf16), 4 rows per load instr, 16 in flight.
__global__ __launch_bounds__(256) void k_gather_relu(const unsigned short* __restrict__ Y,
                                                     const int* __restrict__ rowptr,
                                                     const int* __restrict__ csr,
                                                     float* __restrict__ RO, int n)
{
    int lane = threadIdx.x & 63;
    int grp = lane >> 4, sub = lane & 15;
    int wid = blockIdx.x * 4 + (threadIdx.x >> 6);
    int nw = gridDim.x * 4;
    for (int node = wid; node < n; node += nw) {
        int e0 = rowptr[node], e1 = rowptr[node + 1];
        float4 a0 = make_float4(0, 0, 0, 0), a1 = a0, a2 = a0, a3 = a0;
        int e = e0;
        for (; e + 16 <= e1; e += 16) {
            int s0 = csr[e + grp],      s1 = csr[e + 4 + grp];
            int s2 = csr[e + 8 + grp],  s3 = csr[e + 12 + grp];
            uint2 p0 = *(const uint2*)(Y + (size_t)s0 * CH + sub * 4);
            uint2 p1 = *(const uint2*)(Y + (size_t)s1 * CH + sub * 4);
            uint2 p2 = *(const uint2*)(Y + (size_t)s2 * CH + sub * 4);
            uint2 p3 = *(const uint2*)(Y + (size_t)s3 * CH + sub * 4);
            bfacc(a0, p0.x, p0.y); bfacc(a1, p1.x, p1.y);
            bfacc(a2, p2.x, p2.y); bfacc(a3, p3.x, p3.y);
        }
        for (; e + 4 <= e1; e += 4) {
            int s = csr[e + grp];
            uint2 p = *(const uint2*)(Y + (size_t)s * CH + sub * 4);
            bfacc(a0, p.x, p.y);
        }
        if (e + grp < e1) {
            int s = csr[e + grp];
            uint2 p = *(const uint2*)(Y + (size_t)s * CH + sub * 4);
            bfacc(a1, p.x, p.y);
        }
        f4add(a0, a1); f4add(a2, a3); f4add(a0, a2);
        a0.x += __shfl_xor(a0.x, 16); a0.y += __shfl_xor(a0.y, 16);
        a0.z += __shfl_xor(a0.z, 16); a0.w += __shfl_xor(a0.w, 16);
        a0.x += __shfl_xor(a0.x, 32); a0.y += __shfl_xor(a0.y, 32);
        a0.z += __shfl_xor(a0.z, 32); a0.w += __shfl_xor(a0.w, 32);
        if (grp == 0) {
            const float4 r = *(const float4*)(RO + (size_t)node * CH + sub * 4);
            float4 h;
            h.x = fmaxf(a0.x + r.x, 0.f); h.y = fmaxf(a0.y + r.y, 0.f);
            h.z = fmaxf(a0.z + r.z, 0.f); h.w = fmaxf(a0.w + r.w, 0.f);
            *(float4*)(RO + (size_t)node * CH + sub * 4) = h;
        }
    }
}

// -------- gather + relu + mean-pool accumulate (layer 2) -------------------
__global__ __launch_bounds__(256) void k_gather_pool(const unsigned short* __restrict__ Y,
                                                     const float* __restrict__ R,
                                                     const int* __restrict__ rowptr,
                                                     const int* __restrict__ csr,
                                                     const int* __restrict__ batch,
                                                     float* __restrict__ sums,
                                                     int n, int chunk)
{
    int lane = threadIdx.x & 63;
    int grp = lane >> 4, sub = lane & 15;
    int wid = blockIdx.x * 4 + (threadIdx.x >> 6);
    int nb = wid * chunk, ne = min(nb + chunk, n);
    float4 run = make_float4(0, 0, 0, 0);
    int gcur = -1;
    for (int node = nb; node < ne; ++node) {
        int e0 = rowptr[node], e1 = rowptr[node + 1];
        float4 a0 = make_float4(0, 0, 0, 0), a1 = a0, a2 = a0, a3 = a0;
        int e = e0;
        for (; e + 16 <= e1; e += 16) {
            int s0 = csr[e + grp],      s1 = csr[e + 4 + grp];
            int s2 = csr[e + 8 + grp],  s3 = csr[e + 12 + grp];
            uint2 p0 = *(const uint2*)(Y + (size_t)s0 * CH + sub * 4);
            uint2 p1 = *(const uint2*)(Y + (size_t)s1 * CH + sub * 4);
            uint2 p2 = *(const uint2*)(Y + (size_t)s2 * CH + sub * 4);
            uint2 p3 = *(const uint2*)(Y + (size_t)s3 * CH + sub * 4);
            bfacc(a0, p0.x, p0.y); bfacc(a1, p1.x, p1.y);
            bfacc(a2, p2.x, p2.y); bfacc(a3, p3.x, p3.y);
        }
        for (; e + 4 <= e1; e += 4) {
            int s = csr[e + grp];
            uint2 p = *(const uint2*)(Y + (size_t)s * CH + sub * 4);
            bfacc(a0, p.x, p.y);
        }
        if (e + grp < e1) {
            int s = csr[e + grp];
            uint2 p = *(const uint2*)(Y + (size_t)s * CH + sub * 4);
            bfacc(a1, p.x, p.y);
        }
        f4add(a0, a1); f4add(a2, a3); f4add(a0, a2);
        a0.x += __shfl_xor(a0.x, 16); a0.y += __shfl_xor(a0.y, 16);
        a0.z += __shfl_xor(a0.z, 16); a0.w += __shfl_xor(a0.w, 16);
        a0.x += __shfl_xor(a0.x, 32); a0.y += __shfl_xor(a0.y, 32);
        a0.z += __shfl_xor(a0.z, 32); a0.w += __shfl_xor(a0.w, 32);
        if (grp == 0) {
            const float4 r = *(const float4*)(R + (size_t)node * CH + sub * 4);
            float4 h;
            h.x = fmaxf(a0.x + r.x, 0.f); h.y = fmaxf(a0.y + r.y, 0.f);
            h.z = fmaxf(a0.z + r.z, 0.f); h.w = fmaxf(a0.w + r.w, 0.f);
            int g = batch[node];
            if (g != gcur) {
                if (gcur >= 0) {
                    atomicAdd(&sums[gcur * CH + sub * 4 + 0], run.x);
                    atomicAdd(&sums[gcur * CH + sub * 4 + 1], run.y);
                    atomicAdd(&sums[gcur * CH + sub * 4 + 2], run.z);
                    atomicAdd(&sums[gcur * CH + sub * 4 + 3], run.w);
                }
                run = make_float4(0, 0, 0, 0);
                gcur = g;
            }
            f4add(run, h);
        }
    }
    if (grp == 0 && gcur >= 0) {
        atomicAdd(&sums[gcur * CH + sub * 4 + 0], run.x);
        atomicAdd(&sums[gcur * CH + sub * 4 + 1], run.y);
        atomicAdd(&sums[gcur * CH + sub * 4 + 2], run.z);
        atomicAdd(&sums[gcur * CH + sub * 4 + 3], run.w);
    }
}

// -------- final head --------------------------------------------------------
__global__ void k_final(const float* __restrict__ sums,
                        const int* __restrict__ batch,
                        const float* __restrict__ Wlin,
                        const float* __restrict__ blin,
                        float* __restrict__ out, int n_nodes)
{
    int t = threadIdx.x;
    if (t >= NG * NC) return;
    int g = t / NC, c = t % NC;
    int lo = 0, hi = n_nodes;
    while (lo < hi) { int mid = (lo + hi) >> 1; if (batch[mid] < g) lo = mid + 1; else hi = mid; }
    int lb = lo;
    lo = 0; hi = n_nodes;
    while (lo < hi) { int mid = (lo + hi) >> 1; if (batch[mid] < g + 1) lo = mid + 1; else hi = mid; }
    int cnt = lo - lb;
    float inv = 1.0f / fmaxf((float)cnt, 1.0f);
    float acc = blin[c];
    for (int k = 0; k < CH; ++k)
        acc += sums[g * CH + k] * inv * Wlin[c * CH + k];
    out[g * NC + c] = acc;
}

extern "C" void kernel_launch(void* const* d_in, const int* in_sizes, int n_in,
                              void* d_out, int out_size, void* d_ws, size_t ws_size,
                              hipStream_t stream)
{
    const float* x      = (const float*)d_in[0];
    const int*   ei     = (const int*)d_in[1];
    const int*   batch  = (const int*)d_in[2];
    const float* W1rel  = (const float*)d_in[3];
    const float* W1root = (const float*)d_in[4];
    const float* b1     = (const float*)d_in[5];
    const float* W2rel  = (const float*)d_in[6];
    const float* W2root = (const float*)d_in[7];
    const float* b2     = (const float*)d_in[8];
    const float* Wlin   = (const float*)d_in[9];
    const float* blin   = (const float*)d_in[10];
    float* out = (float*)d_out;

    int n_nodes = in_sizes[0] / CH;
    int n_edges = in_sizes[1] / 2;
    const int* src = ei;
    const int* dst = ei + n_edges;

    int nb  = (n_nodes + BW - 1) >> SHIFT;          // buckets (<=256)
    int cap = n_edges / nb + 2048;                  // per-bucket capacity

    // workspace: Ybf | H | rowptr | csr | bbuf | bcnt | bbase | sums  (~53 MB)
    unsigned short* Ybf = (unsigned short*)d_ws;
    float* H      = (float*)(Ybf + (size_t)n_nodes * CH);
    int*   rowptr = (int*)(H + (size_t)n_nodes * CH);
    int*   csr    = rowptr + (n_nodes + 1);
    int*   bbuf   = csr + n_edges;
    int*   bcnt   = bbuf + (size_t)nb * cap;
    int*   bbase  = bcnt + 256;
    float* sums   = (float*)(bbase + 257);

    // ---- build CSR (dst -> srcs) via bucketed counting sort ----
    hipMemsetAsync(bcnt, 0, 256 * sizeof(int), stream);
    int b1blocks = (n_edges + EPW - 1) / EPW;
    k_bucket<<<b1blocks, 256, 0, stream>>>(src, dst, bcnt, bbuf, nb, cap, n_edges);
    k_bscan<<<1, 256, 0, stream>>>(bcnt, bbase, rowptr, nb, n_nodes, cap);
    k_build<<<nb, 256, 0, stream>>>(bbuf, bcnt, bbase, rowptr, csr, cap, n_nodes);

    // ---- layer 1 ----
    k_xform<<<2048, 256, 0, stream>>>(x, W1rel, W1root, b1, Ybf, H, n_nodes);
    k_gather_relu<<<2048, 256, 0, stream>>>(Ybf, rowptr, csr, H, n_nodes);

    // ---- layer 2 ----
    k_xform<<<2048, 256, 0, stream>>>(H, W2rel, W2root, b2, Ybf, H, n_nodes);
    hipMemsetAsync(sums, 0, NG * CH * sizeof(float), stream);
    int waves = 2048 * 4;
    int chunk = (n_nodes + waves - 1) / waves;
    k_gather_pool<<<2048, 256, 0, stream>>>(Ybf, H, rowptr, csr, batch, sums, n_nodes, chunk);

    // ---- head ----
    k_final<<<1, NG * NC, 0, stream>>>(sums, batch, Wlin, blin, out, n_nodes);
}

// Round 6
// 237.307 us; speedup vs baseline: 12.9881x; 1.2056x over previous
//
#include <hip/hip_runtime.h>

typedef unsigned short u16;
typedef __attribute__((ext_vector_type(8))) short bf16x8;
typedef __attribute__((ext_vector_type(4))) float f32x4;

constexpr int CH = 64;      // IN_CH == HID == 64
constexpr int NG = 64;      // graphs
constexpr int NC = 10;      // classes
constexpr int SHIFT = 9;    // bucket = 512 nodes
constexpr int BW = 1 << SHIFT;
constexpr int EPW = 8192;   // edges per workgroup in bucket pass

__device__ __forceinline__ void f4add(float4& a, const float4 v) {
    a.x += v.x; a.y += v.y; a.z += v.z; a.w += v.w;
}
__device__ __forceinline__ u16 f2bf(float f) {   // RNE f32->bf16
    unsigned u = __float_as_uint(f);
    u = (u + 0x7FFFu + ((u >> 16) & 1u)) >> 16;
    return (u16)u;
}
__device__ __forceinline__ void bfacc(float4& a, unsigned lo, unsigned hi) {
    a.x += __uint_as_float(lo << 16);
    a.y += __uint_as_float(lo & 0xFFFF0000u);
    a.z += __uint_as_float(hi << 16);
    a.w += __uint_as_float(hi & 0xFFFF0000u);
}

// ---- B1: bin edges by dst bucket; packed record = src | (dstLocal<<17) ----
__global__ __launch_bounds__(256) void k_bucket(const int* __restrict__ src,
                                                const int* __restrict__ dst,
                                                int* __restrict__ bcnt,
                                                int* __restrict__ bbuf,
                                                int nb, int cap, int n_edges)
{
    __shared__ int hist[256];
    __shared__ int cur[256];
    int t = threadIdx.x;
    int e0 = blockIdx.x * EPW;
    int e1 = min(e0 + EPW, n_edges);
    if (t < nb) hist[t] = 0;
    __syncthreads();
    for (int e = e0 + t; e < e1; e += 256)
        atomicAdd(&hist[dst[e] >> SHIFT], 1);
    __syncthreads();
    if (t < nb) cur[t] = atomicAdd(&bcnt[t], hist[t]);   // reserve range
    __syncthreads();
    for (int e = e0 + t; e < e1; e += 256) {
        int d = dst[e];
        int b = d >> SHIFT;
        int pos = atomicAdd(&cur[b], 1);
        if (pos < cap)
            bbuf[(size_t)b * cap + pos] = src[e] | ((d & (BW - 1)) << 17);
    }
}

// ---- scan bucket counts -> bucket csr bases; also rowptr[n] ----------------
__global__ __launch_bounds__(256) void k_bscan(const int* __restrict__ bcnt,
                                               int* __restrict__ bbase,
                                               int* __restrict__ rowptr,
                                               int nb, int n, int cap)
{
    __shared__ int lds[256];
    int t = threadIdx.x;
    int v = (t < nb) ? min(bcnt[t], cap) : 0;
    lds[t] = v;
    __syncthreads();
    for (int off = 1; off < 256; off <<= 1) {
        int u = (t >= off) ? lds[t - off] : 0;
        __syncthreads();
        lds[t] += u;
        __syncthreads();
    }
    if (t < nb) bbase[t] = lds[t] - v;
    if (t == nb - 1) { bbase[nb] = lds[t]; rowptr[n] = lds[t]; }
}

// ---- B2: per-bucket local count + scan + place; contiguous csr window -----
__global__ __launch_bounds__(256) void k_build(const int* __restrict__ bbuf,
                                               const int* __restrict__ bcnt,
                                               const int* __restrict__ bbase,
                                               int* __restrict__ rowptr,
                                               int* __restrict__ csr,
                                               int cap, int n)
{
    __shared__ int hist[BW];
    __shared__ int cur[BW];
    __shared__ int psum[256];
    int b = blockIdx.x;
    int t = threadIdx.x;
    int cnt = min(bcnt[b], cap);
    int base = bbase[b];
    const int* mybuf = bbuf + (size_t)b * cap;
    hist[t] = 0; hist[t + 256] = 0;
    __syncthreads();
    for (int i = t; i < cnt; i += 256)
        atomicAdd(&hist[mybuf[i] >> 17], 1);
    __syncthreads();
    int h0 = hist[2 * t], h1 = hist[2 * t + 1];
    int ps = h0 + h1;
    psum[t] = ps;
    __syncthreads();
    for (int off = 1; off < 256; off <<= 1) {
        int u = (t >= off) ? psum[t - off] : 0;
        __syncthreads();
        psum[t] += u;
        __syncthreads();
    }
    int e0 = psum[t] - ps;                 // exclusive start of pair (2t,2t+1)
    int nodeBase = b * BW;
    cur[2 * t]     = base + e0;
    cur[2 * t + 1] = base + e0 + h0;
    if (nodeBase + 2 * t < n)     rowptr[nodeBase + 2 * t]     = base + e0;
    if (nodeBase + 2 * t + 1 < n) rowptr[nodeBase + 2 * t + 1] = base + e0 + h0;
    __syncthreads();
    for (int i = t; i < cnt; i += 256) {
        int v = mybuf[i];
        int pos = atomicAdd(&cur[v >> 17], 1);
        csr[pos] = v & 0x1FFFF;
    }
}

// -------- MFMA dense: Y = in@Wrel^T (bf16), R = in@Wroot^T + b (bf16) ------
// One wave per 16-node group (2 groups/wave). A-frag: lane holds row (l&15),
// 8 contiguous k at 8*(l>>4) per 32-k step. B-frag: same mapping on W rows
// (consistent k-permutation on both operands cancels vs HW slot order).
// C/D (HW-verified): col = lane&15, row = (lane>>4)*4 + reg.
// NOTE: in_ may alias R (in-place layer-2); each wave reads its rows before
// storing them, and no other wave touches them. No __restrict__ on in_/R.
template<bool BF16IN>
__global__ __launch_bounds__(256) void k_xform_mfma(const void* in_,
                                                    const float* __restrict__ Wrel,
                                                    const float* __restrict__ Wroot,
                                                    const float* __restrict__ bias,
                                                    u16* __restrict__ Y,
                                                    u16* R, int n, int ngroups)
{
    int lane = threadIdx.x & 63;
    int lr = lane & 15;      // A-row / B-row(=out ch) / D-col
    int g  = lane >> 4;      // k-group

    // weight fragments in VGPRs: [mat][n-tile][k-step]
    bf16x8 wf[2][4][2];
    const float* Wm[2] = { Wrel, Wroot };
#pragma unroll
    for (int m = 0; m < 2; ++m)
#pragma unroll
        for (int t = 0; t < 4; ++t)
#pragma unroll
            for (int kt = 0; kt < 2; ++kt) {
                const float* p = Wm[m] + (16 * t + lr) * CH + 32 * kt + 8 * g;
                bf16x8 v;
#pragma unroll
                for (int j = 0; j < 8; ++j) v[j] = (short)f2bf(p[j]);
                wf[m][t][kt] = v;
            }
    float bvt[4];
#pragma unroll
    for (int t = 0; t < 4; ++t) bvt[t] = bias[16 * t + lr];

    int wid = blockIdx.x * 4 + (threadIdx.x >> 6);
#pragma unroll
    for (int gi = 0; gi < 2; ++gi) {
        int grp = wid * 2 + gi;
        if (grp >= ngroups) return;
        int gbase = grp * 16;
        int arow = gbase + lr;
        if (arow >= n) arow = n - 1;

        bf16x8 af[2];
#pragma unroll
        for (int kt = 0; kt < 2; ++kt) {
            if (BF16IN) {
                const u16* hp = (const u16*)in_ + (size_t)arow * CH + kt * 32 + 8 * g;
                af[kt] = *(const bf16x8*)hp;
            } else {
                const float* xp = (const float*)in_ + (size_t)arow * CH + kt * 32 + 8 * g;
                bf16x8 v;
#pragma unroll
                for (int j = 0; j < 8; ++j) v[j] = (short)f2bf(xp[j]);
                af[kt] = v;
            }
        }

        f32x4 z = { 0.f, 0.f, 0.f, 0.f };
        f32x4 aY[4] = { z, z, z, z };
        f32x4 aR[4] = { z, z, z, z };
#pragma unroll
        for (int kt = 0; kt < 2; ++kt)
#pragma unroll
            for (int t = 0; t < 4; ++t) {
                aY[t] = __builtin_amdgcn_mfma_f32_16x16x32_bf16(af[kt], wf[0][t][kt], aY[t], 0, 0, 0);
                aR[t] = __builtin_amdgcn_mfma_f32_16x16x32_bf16(af[kt], wf[1][t][kt], aR[t], 0, 0, 0);
            }

#pragma unroll
        for (int t = 0; t < 4; ++t)
#pragma unroll
            for (int r = 0; r < 4; ++r) {
                int node = gbase + 4 * g + r;
                if (node < n) {
                    Y[(size_t)node * CH + 16 * t + lr] = f2bf(aY[t][r]);
                    R[(size_t)node * CH + 16 * t + lr] = f2bf(aR[t][r] + bvt[t]);
                }
            }
    }
}

// -------- pure gather (bf16 rows): h[node] = relu(sum Y[src] + RO[node]) ---
// 16 lanes per row (uint2 = 4 bf16), 4 rows per load instr, 16 in flight.
// RO (bf16) is read then overwritten in place by the owning wave.
__global__ __launch_bounds__(256) void k_gather_relu(const u16* __restrict__ Y,
                                                     const int* __restrict__ rowptr,
                                                     const int* __restrict__ csr,
                                                     u16* __restrict__ RO, int n)
{
    int lane = threadIdx.x & 63;
    int grp = lane >> 4, sub = lane & 15;
    int wid = blockIdx.x * 4 + (threadIdx.x >> 6);
    int nw = gridDim.x * 4;
    for (int node = wid; node < n; node += nw) {
        int e0 = rowptr[node], e1 = rowptr[node + 1];
        float4 a0 = make_float4(0, 0, 0, 0), a1 = a0, a2 = a0, a3 = a0;
        int e = e0;
        for (; e + 16 <= e1; e += 16) {
            int s0 = csr[e + grp],      s1 = csr[e + 4 + grp];
            int s2 = csr[e + 8 + grp],  s3 = csr[e + 12 + grp];
            uint2 p0 = *(const uint2*)(Y + (size_t)s0 * CH + sub * 4);
            uint2 p1 = *(const uint2*)(Y + (size_t)s1 * CH + sub * 4);
            uint2 p2 = *(const uint2*)(Y + (size_t)s2 * CH + sub * 4);
            uint2 p3 = *(const uint2*)(Y + (size_t)s3 * CH + sub * 4);
            bfacc(a0, p0.x, p0.y); bfacc(a1, p1.x, p1.y);
            bfacc(a2, p2.x, p2.y); bfacc(a3, p3.x, p3.y);
        }
        for (; e + 4 <= e1; e += 4) {
            int s = csr[e + grp];
            uint2 p = *(const uint2*)(Y + (size_t)s * CH + sub * 4);
            bfacc(a0, p.x, p.y);
        }
        if (e + grp < e1) {
            int s = csr[e + grp];
            uint2 p = *(const uint2*)(Y + (size_t)s * CH + sub * 4);
            bfacc(a1, p.x, p.y);
        }
        f4add(a0, a1); f4add(a2, a3); f4add(a0, a2);
        a0.x += __shfl_xor(a0.x, 16); a0.y += __shfl_xor(a0.y, 16);
        a0.z += __shfl_xor(a0.z, 16); a0.w += __shfl_xor(a0.w, 16);
        a0.x += __shfl_xor(a0.x, 32); a0.y += __shfl_xor(a0.y, 32);
        a0.z += __shfl_xor(a0.z, 32); a0.w += __shfl_xor(a0.w, 32);
        if (grp == 0) {
            uint2 pr = *(const uint2*)(RO + (size_t)node * CH + sub * 4);
            float4 r = make_float4(0, 0, 0, 0);
            bfacc(r, pr.x, pr.y);
            float4 h;
            h.x = fmaxf(a0.x + r.x, 0.f); h.y = fmaxf(a0.y + r.y, 0.f);
            h.z = fmaxf(a0.z + r.z, 0.f); h.w = fmaxf(a0.w + r.w, 0.f);
            uint2 o;
            o.x = (unsigned)f2bf(h.x) | ((unsigned)f2bf(h.y) << 16);
            o.y = (unsigned)f2bf(h.z) | ((unsigned)f2bf(h.w) << 16);
            *(uint2*)(RO + (size_t)node * CH + sub * 4) = o;
        }
    }
}

// -------- gather + relu + mean-pool accumulate (layer 2) -------------------
__global__ __launch_bounds__(256) void k_gather_pool(const u16* __restrict__ Y,
                                                     const u16* __restrict__ R,
                                                     const int* __restrict__ rowptr,
                                                     const int* __restrict__ csr,
                                                     const int* __restrict__ batch,
                                                     float* __restrict__ sums,
                                                     int n, int chunk)
{
    int lane = threadIdx.x & 63;
    int grp = lane >> 4, sub = lane & 15;
    int wid = blockIdx.x * 4 + (threadIdx.x >> 6);
    int nb = wid * chunk, ne = min(nb + chunk, n);
    float4 run = make_float4(0, 0, 0, 0);
    int gcur = -1;
    for (int node = nb; node < ne; ++node) {
        int e0 = rowptr[node], e1 = rowptr[node + 1];
        float4 a0 = make_float4(0, 0, 0, 0), a1 = a0, a2 = a0, a3 = a0;
        int e = e0;
        for (; e + 16 <= e1; e += 16) {
            int s0 = csr[e + grp],      s1 = csr[e + 4 + grp];
            int s2 = csr[e + 8 + grp],  s3 = csr[e + 12 + grp];
            uint2 p0 = *(const uint2*)(Y + (size_t)s0 * CH + sub * 4);
            uint2 p1 = *(const uint2*)(Y + (size_t)s1 * CH + sub * 4);
            uint2 p2 = *(const uint2*)(Y + (size_t)s2 * CH + sub * 4);
            uint2 p3 = *(const uint2*)(Y + (size_t)s3 * CH + sub * 4);
            bfacc(a0, p0.x, p0.y); bfacc(a1, p1.x, p1.y);
            bfacc(a2, p2.x, p2.y); bfacc(a3, p3.x, p3.y);
        }
        for (; e + 4 <= e1; e += 4) {
            int s = csr[e + grp];
            uint2 p = *(const uint2*)(Y + (size_t)s * CH + sub * 4);
            bfacc(a0, p.x, p.y);
        }
        if (e + grp < e1) {
            int s = csr[e + grp];
            uint2 p = *(const uint2*)(Y + (size_t)s * CH + sub * 4);
            bfacc(a1, p.x, p.y);
        }
        f4add(a0, a1); f4add(a2, a3); f4add(a0, a2);
        a0.x += __shfl_xor(a0.x, 16); a0.y += __shfl_xor(a0.y, 16);
        a0.z += __shfl_xor(a0.z, 16); a0.w += __shfl_xor(a0.w, 16);
        a0.x += __shfl_xor(a0.x, 32); a0.y += __shfl_xor(a0.y, 32);
        a0.z += __shfl_xor(a0.z, 32); a0.w += __shfl_xor(a0.w, 32);
        if (grp == 0) {
            uint2 pr = *(const uint2*)(R + (size_t)node * CH + sub * 4);
            float4 r = make_float4(0, 0, 0, 0);
            bfacc(r, pr.x, pr.y);
            float4 h;
            h.x = fmaxf(a0.x + r.x, 0.f); h.y = fmaxf(a0.y + r.y, 0.f);
            h.z = fmaxf(a0.z + r.z, 0.f); h.w = fmaxf(a0.w + r.w, 0.f);
            int g = batch[node];
            if (g != gcur) {
                if (gcur >= 0) {
                    atomicAdd(&sums[gcur * CH + sub * 4 + 0], run.x);
                    atomicAdd(&sums[gcur * CH + sub * 4 + 1], run.y);
                    atomicAdd(&sums[gcur * CH + sub * 4 + 2], run.z);
                    atomicAdd(&sums[gcur * CH + sub * 4 + 3], run.w);
                }
                run = make_float4(0, 0, 0, 0);
                gcur = g;
            }
            f4add(run, h);
        }
    }
    if (grp == 0 && gcur >= 0) {
        atomicAdd(&sums[gcur * CH + sub * 4 + 0], run.x);
        atomicAdd(&sums[gcur * CH + sub * 4 + 1], run.y);
        atomicAdd(&sums[gcur * CH + sub * 4 + 2], run.z);
        atomicAdd(&sums[gcur * CH + sub * 4 + 3], run.w);
    }
}

// -------- final head --------------------------------------------------------
__global__ void k_final(const float* __restrict__ sums,
                        const int* __restrict__ batch,
                        const float* __restrict__ Wlin,
                        const float* __restrict__ blin,
                        float* __restrict__ out, int n_nodes)
{
    int t = threadIdx.x;
    if (t >= NG * NC) return;
    int g = t / NC, c = t % NC;
    int lo = 0, hi = n_nodes;
    while (lo < hi) { int mid = (lo + hi) >> 1; if (batch[mid] < g) lo = mid + 1; else hi = mid; }
    int lb = lo;
    lo = 0; hi = n_nodes;
    while (lo < hi) { int mid = (lo + hi) >> 1; if (batch[mid] < g + 1) lo = mid + 1; else hi = mid; }
    int cnt = lo - lb;
    float inv = 1.0f / fmaxf((float)cnt, 1.0f);
    float acc = blin[c];
    for (int k = 0; k < CH; ++k)
        acc += sums[g * CH + k] * inv * Wlin[c * CH + k];
    out[g * NC + c] = acc;
}

extern "C" void kernel_launch(void* const* d_in, const int* in_sizes, int n_in,
                              void* d_out, int out_size, void* d_ws, size_t ws_size,
                              hipStream_t stream)
{
    const float* x      = (const float*)d_in[0];
    const int*   ei     = (const int*)d_in[1];
    const int*   batch  = (const int*)d_in[2];
    const float* W1rel  = (const float*)d_in[3];
    const float* W1root = (const float*)d_in[4];
    const float* b1     = (const float*)d_in[5];
    const float* W2rel  = (const float*)d_in[6];
    const float* W2root = (const float*)d_in[7];
    const float* b2     = (const float*)d_in[8];
    const float* Wlin   = (const float*)d_in[9];
    const float* blin   = (const float*)d_in[10];
    float* out = (float*)d_out;

    int n_nodes = in_sizes[0] / CH;
    int n_edges = in_sizes[1] / 2;
    const int* src = ei;
    const int* dst = ei + n_edges;

    int nb  = (n_nodes + BW - 1) >> SHIFT;          // buckets (<=256)
    int cap = n_edges / nb + 2048;                  // per-bucket capacity

    // workspace: Ybf | Rbf(H) | rowptr | csr | bbuf | bcnt | bbase | sums (~40MB)
    u16*   Ybf    = (u16*)d_ws;
    u16*   Rbf    = Ybf + (size_t)n_nodes * CH;
    int*   rowptr = (int*)(Rbf + (size_t)n_nodes * CH);
    int*   csr    = rowptr + (n_nodes + 1);
    int*   bbuf   = csr + n_edges;
    int*   bcnt   = bbuf + (size_t)nb * cap;
    int*   bbase  = bcnt + 256;
    float* sums   = (float*)(bbase + 257);

    // ---- build CSR (dst -> srcs) via bucketed counting sort ----
    hipMemsetAsync(bcnt, 0, 256 * sizeof(int), stream);
    int b1blocks = (n_edges + EPW - 1) / EPW;
    k_bucket<<<b1blocks, 256, 0, stream>>>(src, dst, bcnt, bbuf, nb, cap, n_edges);
    k_bscan<<<1, 256, 0, stream>>>(bcnt, bbase, rowptr, nb, n_nodes, cap);
    k_build<<<nb, 256, 0, stream>>>(bbuf, bcnt, bbase, rowptr, csr, cap, n_nodes);

    int ngroups = (n_nodes + 15) / 16;
    int xblocks = (ngroups + 7) / 8;                // 4 waves x 2 groups

    // ---- layer 1 ----
    k_xform_mfma<false><<<xblocks, 256, 0, stream>>>(x, W1rel, W1root, b1,
                                                     Ybf, Rbf, n_nodes, ngroups);
    k_gather_relu<<<2048, 256, 0, stream>>>(Ybf, rowptr, csr, Rbf, n_nodes);

    // ---- layer 2 ----
    k_xform_mfma<true><<<xblocks, 256, 0, stream>>>(Rbf, W2rel, W2root, b2,
                                                    Ybf, Rbf, n_nodes, ngroups);
    hipMemsetAsync(sums, 0, NG * CH * sizeof(float), stream);
    int waves = 2048 * 4;
    int chunk = (n_nodes + waves - 1) / waves;
    k_gather_pool<<<2048, 256, 0, stream>>>(Ybf, Rbf, rowptr, csr, batch, sums, n_nodes, chunk);

    // ---- head ----
    k_final<<<1, NG * NC, 0, stream>>>(sums, batch, Wlin, blin, out, n_nodes);
}